// Round 6
// baseline (213.294 us; speedup 1.0000x reference)
//
#include <hip/hip_runtime.h>
#include <hip/hip_bf16.h>
#include <cstdint>
#include <cstddef>

#define L_SEQ 4096
#define BATCH_N 4
#define HID 1024
#define DH 256
// log2(0.96875)
#define LOG2_GAMMA (-0.045803689613124953f)
// 0.96875^-32
#define INV_GAMMA32 (2.7620582f)

typedef __attribute__((ext_vector_type(8))) short short8;
typedef __attribute__((ext_vector_type(4))) float floatx4;

__device__ __forceinline__ unsigned short f2bf(float f) {
    union { float f; unsigned int u; } v; v.f = f;
    unsigned int r = (v.u + 0x7FFFu + ((v.u >> 16) & 1u)) >> 16;  // RNE
    return (unsigned short)r;
}

__device__ __forceinline__ void async_copy16(const unsigned short* gsrc,
                                             unsigned short* lds) {
    __builtin_amdgcn_global_load_lds(
        (const __attribute__((address_space(1))) unsigned int*)gsrc,
        (__attribute__((address_space(3))) unsigned int*)lds, 16, 0, 0);
}

// ---------------------------------------------------------------------------
// Kernel P: fused preprocessing. Block-range sections:
//   [0,16384)        : X fp32 -> bf16                  (convert_x)
//   [16384,18432)    : xpos coefficient tables          (xpos_table)
//   [18432,18624)    : W transpose+convert -> Wt        (transpose_w)
//   [18624,19136)    : zero O (4,194,304 floats = 16 MB; FIXED round-6 —
//                      round 5 zeroed 4x the buffer -> OOB fault)
// All sections independent; later kernels depend only on stream order.
// ---------------------------------------------------------------------------
__global__ __launch_bounds__(256) void prep_kernel(
    const float* __restrict__ X, unsigned short* __restrict__ Xb,
    float2* __restrict__ tabQ, float2* __restrict__ tabK,
    const float* __restrict__ WQ, const float* __restrict__ WK,
    const float* __restrict__ WV, unsigned short* __restrict__ Wt,
    float* __restrict__ O)
{
    __shared__ float Ts[64][68];   // used by the transpose section only
    const int bid = blockIdx.x;
    const int t   = threadIdx.x;

    if (bid < 16384) {
        // ---- convert X ----
        const int i = (bid * 256 + t) * 4;
        const float4 v = *(const float4*)&X[i];
        ushort4 p;
        p.x = f2bf(v.x); p.y = f2bf(v.y); p.z = f2bf(v.z); p.w = f2bf(v.w);
        *(ushort4*)&Xb[i] = p;
    } else if (bid < 18432) {
        // ---- xpos tables: tab[i2][pos], pos-major ----
        const int gid = (bid - 16384) * 256 + t;          // 0 .. 524287
        const int i2  = gid >> 12;                        // 0..127
        const int pos = gid & (L_SEQ - 1);
        const float e   = (float)pos * (1.0f / 512.0f);
        const float sb  = ((float)(2 * i2) + 102.4f) * (1.0f / 358.4f);
        const float scQ = exp2f(log2f(sb) * e);
        const float scK = 1.0f / scQ;
        const float invf = exp2f(-13.287712379549449f *
                                 ((float)i2 * (1.0f / 128.0f)));
        float s, c;
        sincosf((float)pos * invf, &s, &c);
        tabQ[gid] = make_float2(c * scQ, s * scQ);
        tabK[gid] = make_float2(c * scK, s * scK);
    } else if (bid < 18624) {
        // ---- W transpose: [1024][256] fp32 -> Wt bf16 [768][1024] ----
        const int idx = bid - 18432;          // 0..191
        const int n0 = (idx % 12) * 64;       // 0..704
        const int k0 = (idx / 12) * 64;       // 0..960
        const int seg = n0 >> 8;
        const float* __restrict__ W = (seg == 0) ? WQ : (seg == 1) ? WK : WV;
        const int nl0 = n0 & 255;

        const int r  = t >> 4;          // 0..15
        const int c4 = (t & 15) * 4;
        #pragma unroll
        for (int i = 0; i < 4; ++i) {
            const int kk = r + i * 16;
            const float4 v = *(const float4*)&W[(size_t)(k0 + kk) * DH + nl0 + c4];
            Ts[c4 + 0][kk] = v.x;
            Ts[c4 + 1][kk] = v.y;
            Ts[c4 + 2][kk] = v.z;
            Ts[c4 + 3][kk] = v.w;
        }
        __syncthreads();
        const int rn = t >> 3;          // 0..31
        const int c8 = (t & 7) * 8;
        #pragma unroll
        for (int i = 0; i < 2; ++i) {
            const int rr = rn + i * 32;
            ushort4 p0, p1;
            p0.x = f2bf(Ts[rr][c8 + 0]); p0.y = f2bf(Ts[rr][c8 + 1]);
            p0.z = f2bf(Ts[rr][c8 + 2]); p0.w = f2bf(Ts[rr][c8 + 3]);
            p1.x = f2bf(Ts[rr][c8 + 4]); p1.y = f2bf(Ts[rr][c8 + 5]);
            p1.z = f2bf(Ts[rr][c8 + 6]); p1.w = f2bf(Ts[rr][c8 + 7]);
            unsigned short* dst = &Wt[(size_t)(n0 + rr) * HID + k0 + c8];
            *(ushort4*)dst       = p0;
            *(ushort4*)(dst + 4) = p1;
        }
    } else {
        // ---- zero O: 512 blocks x 256 thr x 8 float4 = 4,194,304 floats ----
        const int gid = (bid - 18624) * 256 + t;          // 0 .. 131071
        float4 z = (float4){0.f, 0.f, 0.f, 0.f};
        float4* dst = (float4*)O + (size_t)gid * 8;
        #pragma unroll
        for (int i = 0; i < 8; ++i) dst[i] = z;
    }
}

// ---------------------------------------------------------------------------
// Kernel C: QKV projection via bf16 MFMA, output-transposed D[n][pos].
//   Triple-buffered LDS pipeline, counted vmcnt, raw s_barrier; xpos epilogue
//   via precomputed tables.
//   Round 5/6: conflict-free LDS fragment layout. global_load_lds writes
//   linearly (base + lane*16B), so the lane->global-source mapping is
//   permuted (rule #21): LDS chunk semantic layout per 16-row half-tile is
//   [kq 4][r16 16][16B] (lane = kq*16 + r16). Frag reads become 256B
//   contiguous per quad -> exact 2-way bank aliasing (free), killing the
//   8-way conflict (SQ_LDS_BANK_CONFLICT was 3.15M/dispatch).
// ---------------------------------------------------------------------------
__global__ __launch_bounds__(256) void gemm_qkv_kernel(
    const unsigned short* __restrict__ Wt,   // [768][1024]
    const unsigned short* __restrict__ Xb,   // [16384][1024]
    const float2* __restrict__ tabQ,         // [128][4096]
    const float2* __restrict__ tabK,         // [128][4096]
    unsigned short* __restrict__ Qo,
    unsigned short* __restrict__ Ko,
    unsigned short* __restrict__ VtG)
{
    __shared__ unsigned short Wa[3][128][32];   // 24 KB  [buf][.][.] (opaque)
    __shared__ unsigned short Xs[3][128][32];   // 24 KB

    // XCD swizzle: 768 = 8 xcd * 96; per-XCD 96 blocks = 16 p-tiles x 6 n-tiles
    const int dblk = blockIdx.x;
    const int xcd  = dblk & 7;
    const int sq   = dblk >> 3;        // 0..95
    const int by   = xcd * 16 + sq / 6;
    const int bx   = sq % 6;

    const int n0 = bx * 128;   // 0..640
    const int p0 = by * 128;   // 0..16256
    const int t    = threadIdx.x;
    const int w    = t >> 6;
    const int lane = t & 63;
    const int quad = lane >> 4;
    const int l16  = lane & 15;
    const int wn   = (w & 1) * 64;
    const int wp   = (w >> 1) * 64;

    // permuted staging source (linear LDS dest): lane = kq*16 + r16
    const int r16 = lane & 15;          // global row within 16-row half-tile
    const int kq8 = (lane >> 4) * 8;    // global col slot (shorts)

    floatx4 acc[4][4];
    #pragma unroll
    for (int i = 0; i < 4; ++i)
        #pragma unroll
        for (int j = 0; j < 4; ++j) acc[i][j] = (floatx4){0.f, 0.f, 0.f, 0.f};

    const int NT = HID / 32;   // 32 K-steps

    // issue the 4 async loads (2 arrays x 2 half-tiles) for K-tile `kt`
    auto stage = [&](int buf, int kt) {
        const int k0 = kt * 32;
        #pragma unroll
        for (int is = 0; is < 2; ++is) {
            const unsigned short* ga =
                &Wt[(size_t)(n0 + w * 32 + is * 16 + r16) * HID + k0 + kq8];
            const unsigned short* gb =
                &Xb[(size_t)(p0 + w * 32 + is * 16 + r16) * HID + k0 + kq8];
            async_copy16(ga, &Wa[buf][w * 32 + is * 16][0]);
            async_copy16(gb, &Xs[buf][w * 32 + is * 16][0]);
        }
    };

    // prologue: 2 tiles in flight (8 outstanding vmem ops per thread)
    stage(0, 0);
    stage(1, 1);

    for (int kt = 0; kt < NT; ++kt) {
        const int buf = kt % 3;
        // wait until this tile's 4 loads have landed; keep next tile's 4
        // in flight across the barrier (counted vmcnt, never 0 mid-loop)
        if (kt + 1 < NT)
            asm volatile("s_waitcnt vmcnt(4)" ::: "memory");
        else
            asm volatile("s_waitcnt vmcnt(0)" ::: "memory");
        __builtin_amdgcn_s_barrier();

        // issue prefetch for tile kt+2 (overwrites buf (kt+2)%3 == (kt-1)%3,
        // whose readers all finished before the barrier above)
        if (kt + 2 < NT) stage((kt + 2) % 3, kt + 2);

        // frag reads from the permuted layout:
        //   byte = rb*1024 + quad*256 + l16*16, rb = half-tile index
        const char* wbp = (const char*)&Wa[buf][0][0];
        const char* xbp = (const char*)&Xs[buf][0][0];
        short8 af[4], bfv[4];
        #pragma unroll
        for (int nt = 0; nt < 4; ++nt)
            af[nt] = *(const short8*)(wbp + ((w & 1) * 4 + nt) * 1024 +
                                      quad * 256 + l16 * 16);
        #pragma unroll
        for (int pt = 0; pt < 4; ++pt)
            bfv[pt] = *(const short8*)(xbp + ((w >> 1) * 4 + pt) * 1024 +
                                       quad * 256 + l16 * 16);
        #pragma unroll
        for (int nt = 0; nt < 4; ++nt)
            #pragma unroll
            for (int pt = 0; pt < 4; ++pt)
                acc[nt][pt] = __builtin_amdgcn_mfma_f32_16x16x32_bf16(
                    af[nt], bfv[pt], acc[nt][pt], 0, 0, 0);
    }

    // ---- epilogue ----
    const int seg = n0 >> 8;     // 0=Q 1=K 2=V
    const float2* __restrict__ tab = (seg == 1) ? tabK : tabQ;
    #pragma unroll
    for (int nt = 0; nt < 4; ++nt) {
        const int nfeat = n0 + wn + nt * 16 + quad * 4;  // feat of reg g=0
        const int d0 = nfeat & 255;                      // segment-local
        #pragma unroll
        for (int pt = 0; pt < 4; ++pt) {
            const int pg  = p0 + wp + pt * 16 + l16;     // global row
            const int b   = pg >> 12;
            const int pos = pg & (L_SEQ - 1);
            if (seg == 2) {
                #pragma unroll
                for (int g = 0; g < 4; ++g)
                    VtG[(((size_t)(b * 256 + d0 + g)) << 12) + pos] =
                        f2bf(acc[nt][pt][g]);
            } else {
                float res[4];
                #pragma unroll
                for (int h = 0; h < 4; h += 2) {
                    const int i2 = (d0 + h) >> 1;
                    const float2 tc = tab[(i2 << 12) + pos];
                    const float cs = tc.x, ss = tc.y;
                    const float xe = acc[nt][pt][h], xo = acc[nt][pt][h + 1];
                    res[h]     = xe * cs - xo * ss;
                    res[h + 1] = xo * cs + xe * ss;
                }
                ushort4 pk;
                pk.x = f2bf(res[0]); pk.y = f2bf(res[1]);
                pk.z = f2bf(res[2]); pk.w = f2bf(res[3]);
                unsigned short* orow =
                    ((seg == 0) ? Qo : Ko) + (size_t)pg * DH + d0;
                *(ushort4*)orow = pk;
            }
        }
    }
}

// ---------------------------------------------------------------------------
// Kernel D: windowed retention via bf16 MFMA (unchanged from round 4:
// swapped QK^T, in-register P redistribution via ds_bpermute, Q in regs,
// running multiplicative decay, z2-split + atomicAdd into zeroed O).
// ---------------------------------------------------------------------------
__global__ __launch_bounds__(256) void retention_kernel(
    const unsigned short* __restrict__ Q,
    const unsigned short* __restrict__ K,
    const unsigned short* __restrict__ VtG,
    float* __restrict__ O)
{
    __shared__ short Ks[32][264];    // 16.5 KB
    __shared__ short Vt[256][40];    // 20 KB

    const int dblk = blockIdx.x;
    const int xcd  = dblk & 7;
    const int sq   = dblk >> 3;           // 0..63
    const int qt   = xcd * 8 + (sq & 7);  // 0..63
    const int b    = (sq >> 3) & 3;
    const int z    = sq >> 5;             // 0 = far half, 1 = near half

    const int t  = threadIdx.x;
    const int q0 = qt * 64;

    const int w    = t >> 6;
    const int lane = t & 63;
    const int quad = lane >> 4;
    const int l16  = lane & 15;
    const int w16  = w * 16;

    const size_t rbase = (size_t)b * L_SEQ * DH;
    const size_t vbase = ((size_t)b * DH) << 12;

    // full window [kst, q0+64); length is always a multiple of 64
    int kst = q0 - 512; if (kst < 0) kst = 0;
    const int half32 = ((q0 + 64 - kst) >> 6) << 5;   // (nsteps/2)*32
    const int kbeg = kst + (z ? half32 : 0);
    const int kfin = z ? (q0 + 64) : (kst + half32);

    // Q fragments in registers: B-frag for swapped mfma.
    short8 qf[8];
    {
        const unsigned short* qsrc = Q + rbase + (size_t)(q0 + w16 + l16) * DH;
        #pragma unroll
        for (int dd = 0; dd < 8; ++dd)
            qf[dd] = *(const short8*)&qsrc[dd * 32 + quad * 8];
    }

    // running decay state per (nt,g): d = qpos - kpos at current k0
    int   dint[8];
    float dec[8];
    #pragma unroll
    for (int nt = 0; nt < 2; ++nt)
        #pragma unroll
        for (int g = 0; g < 4; ++g) {
            const int idx = nt * 4 + g;
            dint[idx] = (q0 + w16 + l16) - (kbeg + nt * 16 + quad * 4 + g);
            dec[idx]  = exp2f((float)dint[idx] * LOG2_GAMMA);
        }

    floatx4 o[16];
    #pragma unroll
    for (int f = 0; f < 16; ++f) o[f] = (floatx4){0.f, 0.f, 0.f, 0.f};

    // bpermute source-lane byte indices (constant per lane)
    const int s0   = (quad & 1) * 2;
    const int idxA = (s0 * 16 + l16) * 4;
    const int idxB = idxA + 64;
    const bool lo  = (quad < 2);   // target k-subtile nt = quad>>1

    for (int k0 = kbeg; k0 < kfin; k0 += 32) {
        __syncthreads();   // all reads of Ks/Vt from previous step done
        {
            const unsigned short* src = K + rbase + (size_t)k0 * DH;
            #pragma unroll
            for (int i = 0; i < 4; ++i) {
                const int row = i * 8 + (t >> 5);
                const int col = (t & 31) * 8;
                *(uint4*)&Ks[row][col] = *(const uint4*)&src[row * DH + col];
            }
        }
        {
            const int c0   = t >> 2;
            const int koff = (t & 3) * 8;
            #pragma unroll
            for (int i = 0; i < 4; ++i) {
                const int c = c0 + 64 * i;
                *(uint4*)&Vt[c][koff] =
                    *(const uint4*)&VtG[vbase + ((size_t)c << 12) + k0 + koff];
            }
        }
        __syncthreads();   // staging visible

        // ---- swapped QK^T: A = K rows, B = Q regs; 4 independent chains
        floatx4 sA0 = (floatx4){0.f, 0.f, 0.f, 0.f};
        floatx4 sA1 = (floatx4){0.f, 0.f, 0.f, 0.f};
        floatx4 sB0 = (floatx4){0.f, 0.f, 0.f, 0.f};
        floatx4 sB1 = (floatx4){0.f, 0.f, 0.f, 0.f};
        #pragma unroll
        for (int dd = 0; dd < 4; ++dd) {
            const short8 k0f = *(const short8*)&Ks[l16][dd * 32 + quad * 8];
            const short8 k1f = *(const short8*)&Ks[16 + l16][dd * 32 + quad * 8];
            const short8 k0g = *(const short8*)&Ks[l16][(dd + 4) * 32 + quad * 8];
            const short8 k1g = *(const short8*)&Ks[16 + l16][(dd + 4) * 32 + quad * 8];
            sA0 = __builtin_amdgcn_mfma_f32_16x16x32_bf16(k0f, qf[dd], sA0, 0, 0, 0);
            sA1 = __builtin_amdgcn_mfma_f32_16x16x32_bf16(k1f, qf[dd], sA1, 0, 0, 0);
            sB0 = __builtin_amdgcn_mfma_f32_16x16x32_bf16(k0g, qf[dd + 4], sB0, 0, 0, 0);
            sB1 = __builtin_amdgcn_mfma_f32_16x16x32_bf16(k1g, qf[dd + 4], sB1, 0, 0, 0);
        }
        const floatx4 sv0 = sA0 + sB0;   // nt=0: kpos = k0 + quad*4+g
        const floatx4 sv1 = sA1 + sB1;   // nt=1: kpos = k0+16 + quad*4+g

        // ---- decay + pack to bf16 pairs (lane-local)
        unsigned int pk01[2], pk23[2];
        #pragma unroll
        for (int nt = 0; nt < 2; ++nt) {
            const floatx4 sv = nt ? sv1 : sv0;
            float pv[4];
            #pragma unroll
            for (int g = 0; g < 4; ++g) {
                const int idx = nt * 4 + g;
                pv[g] = (dint[idx] >= 0) ? sv[g] * dec[idx] : 0.0f;
            }
            pk01[nt] = ((unsigned int)f2bf(pv[1]) << 16) | (unsigned int)f2bf(pv[0]);
            pk23[nt] = ((unsigned int)f2bf(pv[3]) << 16) | (unsigned int)f2bf(pv[2]);
        }
        #pragma unroll
        for (int i = 0; i < 8; ++i) { dint[i] -= 32; dec[i] *= INV_GAMMA32; }

        // ---- redistribute P to PV A-frag layout: 8 bpermute + 4 selects
        const int a01_0 = __builtin_amdgcn_ds_bpermute(idxA, (int)pk01[0]);
        const int a01_1 = __builtin_amdgcn_ds_bpermute(idxA, (int)pk01[1]);
        const int a23_0 = __builtin_amdgcn_ds_bpermute(idxA, (int)pk23[0]);
        const int a23_1 = __builtin_amdgcn_ds_bpermute(idxA, (int)pk23[1]);
        const int b01_0 = __builtin_amdgcn_ds_bpermute(idxB, (int)pk01[0]);
        const int b01_1 = __builtin_amdgcn_ds_bpermute(idxB, (int)pk01[1]);
        const int b23_0 = __builtin_amdgcn_ds_bpermute(idxB, (int)pk23[0]);
        const int b23_1 = __builtin_amdgcn_ds_bpermute(idxB, (int)pk23[1]);
        union { int u[4]; short8 s8; } af;
        af.u[0] = lo ? a01_0 : a01_1;
        af.u[1] = lo ? a23_0 : a23_1;
        af.u[2] = lo ? b01_0 : b01_1;
        af.u[3] = lo ? b23_0 : b23_1;

        // ---- PV: o[f] += P @ V^T  (A from regs, B from Vt LDS)
        #pragma unroll
        for (int f = 0; f < 16; ++f) {
            const short8 bfr = *(const short8*)&Vt[f * 16 + l16][quad * 8];
            o[f] = __builtin_amdgcn_mfma_f32_16x16x32_bf16(af.s8, bfr, o[f], 0, 0, 0);
        }
    }

    #pragma unroll
    for (int f = 0; f < 16; ++f) {
        #pragma unroll
        for (int g = 0; g < 4; ++g) {
            const int qpos = q0 + w16 + quad * 4 + g;
            atomicAdd(&O[rbase + (size_t)qpos * DH + f * 16 + l16], o[f][g]);
        }
    }
}

// ---------------------------------------------------------------------------
extern "C" void kernel_launch(void* const* d_in, const int* in_sizes, int n_in,
                              void* d_out, int out_size, void* d_ws, size_t ws_size,
                              hipStream_t stream)
{
    const float* X  = (const float*)d_in[0];
    const float* WQ = (const float*)d_in[1];
    const float* WK = (const float*)d_in[2];
    const float* WV = (const float*)d_in[3];
    float* out = (float*)d_out;

    const size_t per = (size_t)BATCH_N * L_SEQ * DH;   // 4,194,304
    unsigned short* Qw  = (unsigned short*)d_ws;
    unsigned short* Kw  = Qw + per;
    unsigned short* Vtw = Kw + per;
    unsigned short* Xbw = Vtw + per;                   // 16,777,216 elems
    unsigned short* Wtw = Xbw + (size_t)16384 * HID;   // 786,432 elems
    float2* tabQ = (float2*)(Wtw + 786432);            // 4 MB (8B-aligned)
    float2* tabK = tabQ + (size_t)128 * L_SEQ;         // 4 MB
    // total workspace: ~68.3 MB

    // one fused prep dispatch: convert X, build tables, transpose W, zero O
    prep_kernel<<<19136, 256, 0, stream>>>(X, Xbw, tabQ, tabK,
                                           WQ, WK, WV, Wtw, out);

    gemm_qkv_kernel<<<768, 256, 0, stream>>>(Wtw, Xbw, tabQ, tabK, Qw, Kw, Vtw);

    retention_kernel<<<512, 256, 0, stream>>>(Qw, Kw, Vtw, out);
}

// Round 7
// 200.819 us; speedup vs baseline: 1.0621x; 1.0621x over previous
//
#include <hip/hip_runtime.h>
#include <hip/hip_bf16.h>
#include <cstdint>
#include <cstddef>

#define L_SEQ 4096
#define BATCH_N 4
#define HID 1024
#define DH 256
// log2(0.96875)
#define LOG2_GAMMA (-0.045803689613124953f)
// 0.96875^-32
#define INV_GAMMA32 (2.7620582f)

typedef __attribute__((ext_vector_type(8))) short short8;
typedef __attribute__((ext_vector_type(4))) float floatx4;

__device__ __forceinline__ unsigned short f2bf(float f) {
    union { float f; unsigned int u; } v; v.f = f;
    unsigned int r = (v.u + 0x7FFFu + ((v.u >> 16) & 1u)) >> 16;  // RNE
    return (unsigned short)r;
}

__device__ __forceinline__ void async_copy16(const unsigned short* gsrc,
                                             unsigned short* lds) {
    __builtin_amdgcn_global_load_lds(
        (const __attribute__((address_space(1))) unsigned int*)gsrc,
        (__attribute__((address_space(3))) unsigned int*)lds, 16, 0, 0);
}

// ---------------------------------------------------------------------------
// Kernel P: fused preprocessing. Block-range sections:
//   [0,16384)        : X fp32 -> bf16                  (convert_x)
//   [16384,18432)    : xpos coefficient tables          (xpos_table)
//   [18432,18624)    : W transpose+convert -> Wt        (transpose_w)
//   [18624,19136)    : zero O (4,194,304 floats = 16 MB)
// ---------------------------------------------------------------------------
__global__ __launch_bounds__(256) void prep_kernel(
    const float* __restrict__ X, unsigned short* __restrict__ Xb,
    float2* __restrict__ tabQ, float2* __restrict__ tabK,
    const float* __restrict__ WQ, const float* __restrict__ WK,
    const float* __restrict__ WV, unsigned short* __restrict__ Wt,
    float* __restrict__ O)
{
    __shared__ float Ts[64][68];   // used by the transpose section only
    const int bid = blockIdx.x;
    const int t   = threadIdx.x;

    if (bid < 16384) {
        // ---- convert X ----
        const int i = (bid * 256 + t) * 4;
        const float4 v = *(const float4*)&X[i];
        ushort4 p;
        p.x = f2bf(v.x); p.y = f2bf(v.y); p.z = f2bf(v.z); p.w = f2bf(v.w);
        *(ushort4*)&Xb[i] = p;
    } else if (bid < 18432) {
        // ---- xpos tables: tab[i2][pos], pos-major ----
        const int gid = (bid - 16384) * 256 + t;          // 0 .. 524287
        const int i2  = gid >> 12;                        // 0..127
        const int pos = gid & (L_SEQ - 1);
        const float e   = (float)pos * (1.0f / 512.0f);
        const float sb  = ((float)(2 * i2) + 102.4f) * (1.0f / 358.4f);
        const float scQ = exp2f(log2f(sb) * e);
        const float scK = 1.0f / scQ;
        const float invf = exp2f(-13.287712379549449f *
                                 ((float)i2 * (1.0f / 128.0f)));
        float s, c;
        sincosf((float)pos * invf, &s, &c);
        tabQ[gid] = make_float2(c * scQ, s * scQ);
        tabK[gid] = make_float2(c * scK, s * scK);
    } else if (bid < 18624) {
        // ---- W transpose: [1024][256] fp32 -> Wt bf16 [768][1024] ----
        const int idx = bid - 18432;          // 0..191
        const int n0 = (idx % 12) * 64;       // 0..704
        const int k0 = (idx / 12) * 64;       // 0..960
        const int seg = n0 >> 8;
        const float* __restrict__ W = (seg == 0) ? WQ : (seg == 1) ? WK : WV;
        const int nl0 = n0 & 255;

        const int r  = t >> 4;          // 0..15
        const int c4 = (t & 15) * 4;
        #pragma unroll
        for (int i = 0; i < 4; ++i) {
            const int kk = r + i * 16;
            const float4 v = *(const float4*)&W[(size_t)(k0 + kk) * DH + nl0 + c4];
            Ts[c4 + 0][kk] = v.x;
            Ts[c4 + 1][kk] = v.y;
            Ts[c4 + 2][kk] = v.z;
            Ts[c4 + 3][kk] = v.w;
        }
        __syncthreads();
        const int rn = t >> 3;          // 0..31
        const int c8 = (t & 7) * 8;
        #pragma unroll
        for (int i = 0; i < 2; ++i) {
            const int rr = rn + i * 32;
            ushort4 p0, p1;
            p0.x = f2bf(Ts[rr][c8 + 0]); p0.y = f2bf(Ts[rr][c8 + 1]);
            p0.z = f2bf(Ts[rr][c8 + 2]); p0.w = f2bf(Ts[rr][c8 + 3]);
            p1.x = f2bf(Ts[rr][c8 + 4]); p1.y = f2bf(Ts[rr][c8 + 5]);
            p1.z = f2bf(Ts[rr][c8 + 6]); p1.w = f2bf(Ts[rr][c8 + 7]);
            unsigned short* dst = &Wt[(size_t)(n0 + rr) * HID + k0 + c8];
            *(ushort4*)dst       = p0;
            *(ushort4*)(dst + 4) = p1;
        }
    } else {
        // ---- zero O: 512 blocks x 256 thr x 8 float4 = 4,194,304 floats ----
        const int gid = (bid - 18624) * 256 + t;          // 0 .. 131071
        float4 z = (float4){0.f, 0.f, 0.f, 0.f};
        float4* dst = (float4*)O + (size_t)gid * 8;
        #pragma unroll
        for (int i = 0; i < 8; ++i) dst[i] = z;
    }
}

// ---------------------------------------------------------------------------
// Kernel C: QKV projection via bf16 MFMA, output-transposed D[n][pos].
//   Triple-buffered LDS pipeline, counted vmcnt, raw s_barrier; xpos epilogue
//   via precomputed tables.
//   ROUND 7: chunk-XOR swizzle that keeps round-4 coalescing. Staging keeps
//   row = lane>>2 (each 4-lane group reads ONE contiguous 64B row-segment —
//   the round-6 regression was breaking this), but the 16B-chunk select is
//   XORed with (row>>1)&3. Frag reads at byte l16*64 + (quad^((l16>>1)&3))*16
//   hit each 16B bank-granule class exactly twice across 16 lanes -> 2-way
//   aliasing = free. Both sides keyed on the same (j>>1)&3 involution.
// ---------------------------------------------------------------------------
__global__ __launch_bounds__(256) void gemm_qkv_kernel(
    const unsigned short* __restrict__ Wt,   // [768][1024]
    const unsigned short* __restrict__ Xb,   // [16384][1024]
    const float2* __restrict__ tabQ,         // [128][4096]
    const float2* __restrict__ tabK,         // [128][4096]
    unsigned short* __restrict__ Qo,
    unsigned short* __restrict__ Ko,
    unsigned short* __restrict__ VtG)
{
    __shared__ unsigned short Wa[3][128][32];   // 24 KB  [buf][.][.] (opaque)
    __shared__ unsigned short Xs[3][128][32];   // 24 KB

    // XCD swizzle: 768 = 8 xcd * 96; per-XCD 96 blocks = 16 p-tiles x 6 n-tiles
    const int dblk = blockIdx.x;
    const int xcd  = dblk & 7;
    const int sq   = dblk >> 3;        // 0..95
    const int by   = xcd * 16 + sq / 6;
    const int bx   = sq % 6;

    const int n0 = bx * 128;   // 0..640
    const int p0 = by * 128;   // 0..16256
    const int t    = threadIdx.x;
    const int w    = t >> 6;
    const int lane = t & 63;
    const int quad = lane >> 4;
    const int l16  = lane & 15;
    const int wn   = (w & 1) * 64;
    const int wp   = (w >> 1) * 64;

    // staging: row = lane>>2 within half-tile (4-lane group = one 64B segment)
    // chunk swizzled by s = (row>>1)&3 = (lane>>3)&3
    const int srow = w * 32 + (lane >> 2);                       // +is*16
    const int scol = (((lane & 3) ^ ((lane >> 3) & 3))) * 8;     // shorts

    floatx4 acc[4][4];
    #pragma unroll
    for (int i = 0; i < 4; ++i)
        #pragma unroll
        for (int j = 0; j < 4; ++j) acc[i][j] = (floatx4){0.f, 0.f, 0.f, 0.f};

    const int NT = HID / 32;   // 32 K-steps

    // issue the 4 async loads (2 arrays x 2 half-tiles) for K-tile `kt`
    auto stage = [&](int buf, int kt) {
        const int k0 = kt * 32;
        #pragma unroll
        for (int is = 0; is < 2; ++is) {
            const unsigned short* ga =
                &Wt[(size_t)(n0 + srow + is * 16) * HID + k0 + scol];
            const unsigned short* gb =
                &Xb[(size_t)(p0 + srow + is * 16) * HID + k0 + scol];
            async_copy16(ga, &Wa[buf][w * 32 + is * 16][0]);
            async_copy16(gb, &Xs[buf][w * 32 + is * 16][0]);
        }
    };

    // prologue: 2 tiles in flight (8 outstanding vmem ops per thread)
    stage(0, 0);
    stage(1, 1);

    // swizzled frag-read chunk offset (bytes)
    const int rsw = (quad ^ ((l16 >> 1) & 3)) << 4;

    for (int kt = 0; kt < NT; ++kt) {
        const int buf = kt % 3;
        // wait until this tile's 4 loads have landed; keep next tile's 4
        // in flight across the barrier (counted vmcnt, never 0 mid-loop)
        if (kt + 1 < NT)
            asm volatile("s_waitcnt vmcnt(4)" ::: "memory");
        else
            asm volatile("s_waitcnt vmcnt(0)" ::: "memory");
        __builtin_amdgcn_s_barrier();

        // issue prefetch for tile kt+2 (overwrites buf (kt+2)%3 == (kt-1)%3,
        // whose readers all finished before the barrier above)
        if (kt + 2 < NT) stage((kt + 2) % 3, kt + 2);

        // frag reads: byte = h*1024 + l16*64 + (quad^((l16>>1)&3))*16,
        // h = half-tile index
        const char* wbp = (const char*)&Wa[buf][0][0];
        const char* xbp = (const char*)&Xs[buf][0][0];
        short8 af[4], bfv[4];
        #pragma unroll
        for (int nt = 0; nt < 4; ++nt)
            af[nt] = *(const short8*)(wbp + ((w & 1) * 4 + nt) * 1024 +
                                      l16 * 64 + rsw);
        #pragma unroll
        for (int pt = 0; pt < 4; ++pt)
            bfv[pt] = *(const short8*)(xbp + ((w >> 1) * 4 + pt) * 1024 +
                                       l16 * 64 + rsw);
        #pragma unroll
        for (int nt = 0; nt < 4; ++nt)
            #pragma unroll
            for (int pt = 0; pt < 4; ++pt)
                acc[nt][pt] = __builtin_amdgcn_mfma_f32_16x16x32_bf16(
                    af[nt], bfv[pt], acc[nt][pt], 0, 0, 0);
    }

    // ---- epilogue ----
    const int seg = n0 >> 8;     // 0=Q 1=K 2=V
    const float2* __restrict__ tab = (seg == 1) ? tabK : tabQ;
    #pragma unroll
    for (int nt = 0; nt < 4; ++nt) {
        const int nfeat = n0 + wn + nt * 16 + quad * 4;  // feat of reg g=0
        const int d0 = nfeat & 255;                      // segment-local
        #pragma unroll
        for (int pt = 0; pt < 4; ++pt) {
            const int pg  = p0 + wp + pt * 16 + l16;     // global row
            const int b   = pg >> 12;
            const int pos = pg & (L_SEQ - 1);
            if (seg == 2) {
                #pragma unroll
                for (int g = 0; g < 4; ++g)
                    VtG[(((size_t)(b * 256 + d0 + g)) << 12) + pos] =
                        f2bf(acc[nt][pt][g]);
            } else {
                float res[4];
                #pragma unroll
                for (int h = 0; h < 4; h += 2) {
                    const int i2 = (d0 + h) >> 1;
                    const float2 tc = tab[(i2 << 12) + pos];
                    const float cs = tc.x, ss = tc.y;
                    const float xe = acc[nt][pt][h], xo = acc[nt][pt][h + 1];
                    res[h]     = xe * cs - xo * ss;
                    res[h + 1] = xo * cs + xe * ss;
                }
                ushort4 pk;
                pk.x = f2bf(res[0]); pk.y = f2bf(res[1]);
                pk.z = f2bf(res[2]); pk.w = f2bf(res[3]);
                unsigned short* orow =
                    ((seg == 0) ? Qo : Ko) + (size_t)pg * DH + d0;
                *(ushort4*)orow = pk;
            }
        }
    }
}

// ---------------------------------------------------------------------------
// Kernel D: windowed retention via bf16 MFMA (unchanged from round 4:
// swapped QK^T, in-register P redistribution via ds_bpermute, Q in regs,
// running multiplicative decay, z2-split + atomicAdd into zeroed O).
// ---------------------------------------------------------------------------
__global__ __launch_bounds__(256) void retention_kernel(
    const unsigned short* __restrict__ Q,
    const unsigned short* __restrict__ K,
    const unsigned short* __restrict__ VtG,
    float* __restrict__ O)
{
    __shared__ short Ks[32][264];    // 16.5 KB
    __shared__ short Vt[256][40];    // 20 KB

    const int dblk = blockIdx.x;
    const int xcd  = dblk & 7;
    const int sq   = dblk >> 3;           // 0..63
    const int qt   = xcd * 8 + (sq & 7);  // 0..63
    const int b    = (sq >> 3) & 3;
    const int z    = sq >> 5;             // 0 = far half, 1 = near half

    const int t  = threadIdx.x;
    const int q0 = qt * 64;

    const int w    = t >> 6;
    const int lane = t & 63;
    const int quad = lane >> 4;
    const int l16  = lane & 15;
    const int w16  = w * 16;

    const size_t rbase = (size_t)b * L_SEQ * DH;
    const size_t vbase = ((size_t)b * DH) << 12;

    // full window [kst, q0+64); length is always a multiple of 64
    int kst = q0 - 512; if (kst < 0) kst = 0;
    const int half32 = ((q0 + 64 - kst) >> 6) << 5;   // (nsteps/2)*32
    const int kbeg = kst + (z ? half32 : 0);
    const int kfin = z ? (q0 + 64) : (kst + half32);

    // Q fragments in registers: B-frag for swapped mfma.
    short8 qf[8];
    {
        const unsigned short* qsrc = Q + rbase + (size_t)(q0 + w16 + l16) * DH;
        #pragma unroll
        for (int dd = 0; dd < 8; ++dd)
            qf[dd] = *(const short8*)&qsrc[dd * 32 + quad * 8];
    }

    // running decay state per (nt,g): d = qpos - kpos at current k0
    int   dint[8];
    float dec[8];
    #pragma unroll
    for (int nt = 0; nt < 2; ++nt)
        #pragma unroll
        for (int g = 0; g < 4; ++g) {
            const int idx = nt * 4 + g;
            dint[idx] = (q0 + w16 + l16) - (kbeg + nt * 16 + quad * 4 + g);
            dec[idx]  = exp2f((float)dint[idx] * LOG2_GAMMA);
        }

    floatx4 o[16];
    #pragma unroll
    for (int f = 0; f < 16; ++f) o[f] = (floatx4){0.f, 0.f, 0.f, 0.f};

    // bpermute source-lane byte indices (constant per lane)
    const int s0   = (quad & 1) * 2;
    const int idxA = (s0 * 16 + l16) * 4;
    const int idxB = idxA + 64;
    const bool lo  = (quad < 2);   // target k-subtile nt = quad>>1

    for (int k0 = kbeg; k0 < kfin; k0 += 32) {
        __syncthreads();   // all reads of Ks/Vt from previous step done
        {
            const unsigned short* src = K + rbase + (size_t)k0 * DH;
            #pragma unroll
            for (int i = 0; i < 4; ++i) {
                const int row = i * 8 + (t >> 5);
                const int col = (t & 31) * 8;
                *(uint4*)&Ks[row][col] = *(const uint4*)&src[row * DH + col];
            }
        }
        {
            const int c0   = t >> 2;
            const int koff = (t & 3) * 8;
            #pragma unroll
            for (int i = 0; i < 4; ++i) {
                const int c = c0 + 64 * i;
                *(uint4*)&Vt[c][koff] =
                    *(const uint4*)&VtG[vbase + ((size_t)c << 12) + k0 + koff];
            }
        }
        __syncthreads();   // staging visible

        // ---- swapped QK^T: A = K rows, B = Q regs; 4 independent chains
        floatx4 sA0 = (floatx4){0.f, 0.f, 0.f, 0.f};
        floatx4 sA1 = (floatx4){0.f, 0.f, 0.f, 0.f};
        floatx4 sB0 = (floatx4){0.f, 0.f, 0.f, 0.f};
        floatx4 sB1 = (floatx4){0.f, 0.f, 0.f, 0.f};
        #pragma unroll
        for (int dd = 0; dd < 4; ++dd) {
            const short8 k0f = *(const short8*)&Ks[l16][dd * 32 + quad * 8];
            const short8 k1f = *(const short8*)&Ks[16 + l16][dd * 32 + quad * 8];
            const short8 k0g = *(const short8*)&Ks[l16][(dd + 4) * 32 + quad * 8];
            const short8 k1g = *(const short8*)&Ks[16 + l16][(dd + 4) * 32 + quad * 8];
            sA0 = __builtin_amdgcn_mfma_f32_16x16x32_bf16(k0f, qf[dd], sA0, 0, 0, 0);
            sA1 = __builtin_amdgcn_mfma_f32_16x16x32_bf16(k1f, qf[dd], sA1, 0, 0, 0);
            sB0 = __builtin_amdgcn_mfma_f32_16x16x32_bf16(k0g, qf[dd + 4], sB0, 0, 0, 0);
            sB1 = __builtin_amdgcn_mfma_f32_16x16x32_bf16(k1g, qf[dd + 4], sB1, 0, 0, 0);
        }
        const floatx4 sv0 = sA0 + sB0;   // nt=0: kpos = k0 + quad*4+g
        const floatx4 sv1 = sA1 + sB1;   // nt=1: kpos = k0+16 + quad*4+g

        // ---- decay + pack to bf16 pairs (lane-local)
        unsigned int pk01[2], pk23[2];
        #pragma unroll
        for (int nt = 0; nt < 2; ++nt) {
            const floatx4 sv = nt ? sv1 : sv0;
            float pv[4];
            #pragma unroll
            for (int g = 0; g < 4; ++g) {
                const int idx = nt * 4 + g;
                pv[g] = (dint[idx] >= 0) ? sv[g] * dec[idx] : 0.0f;
            }
            pk01[nt] = ((unsigned int)f2bf(pv[1]) << 16) | (unsigned int)f2bf(pv[0]);
            pk23[nt] = ((unsigned int)f2bf(pv[3]) << 16) | (unsigned int)f2bf(pv[2]);
        }
        #pragma unroll
        for (int i = 0; i < 8; ++i) { dint[i] -= 32; dec[i] *= INV_GAMMA32; }

        // ---- redistribute P to PV A-frag layout: 8 bpermute + 4 selects
        const int a01_0 = __builtin_amdgcn_ds_bpermute(idxA, (int)pk01[0]);
        const int a01_1 = __builtin_amdgcn_ds_bpermute(idxA, (int)pk01[1]);
        const int a23_0 = __builtin_amdgcn_ds_bpermute(idxA, (int)pk23[0]);
        const int a23_1 = __builtin_amdgcn_ds_bpermute(idxA, (int)pk23[1]);
        const int b01_0 = __builtin_amdgcn_ds_bpermute(idxB, (int)pk01[0]);
        const int b01_1 = __builtin_amdgcn_ds_bpermute(idxB, (int)pk01[1]);
        const int b23_0 = __builtin_amdgcn_ds_bpermute(idxB, (int)pk23[0]);
        const int b23_1 = __builtin_amdgcn_ds_bpermute(idxB, (int)pk23[1]);
        union { int u[4]; short8 s8; } af;
        af.u[0] = lo ? a01_0 : a01_1;
        af.u[1] = lo ? a23_0 : a23_1;
        af.u[2] = lo ? b01_0 : b01_1;
        af.u[3] = lo ? b23_0 : b23_1;

        // ---- PV: o[f] += P @ V^T  (A from regs, B from Vt LDS)
        #pragma unroll
        for (int f = 0; f < 16; ++f) {
            const short8 bfr = *(const short8*)&Vt[f * 16 + l16][quad * 8];
            o[f] = __builtin_amdgcn_mfma_f32_16x16x32_bf16(af.s8, bfr, o[f], 0, 0, 0);
        }
    }

    #pragma unroll
    for (int f = 0; f < 16; ++f) {
        #pragma unroll
        for (int g = 0; g < 4; ++g) {
            const int qpos = q0 + w16 + quad * 4 + g;
            atomicAdd(&O[rbase + (size_t)qpos * DH + f * 16 + l16], o[f][g]);
        }
    }
}

// ---------------------------------------------------------------------------
extern "C" void kernel_launch(void* const* d_in, const int* in_sizes, int n_in,
                              void* d_out, int out_size, void* d_ws, size_t ws_size,
                              hipStream_t stream)
{
    const float* X  = (const float*)d_in[0];
    const float* WQ = (const float*)d_in[1];
    const float* WK = (const float*)d_in[2];
    const float* WV = (const float*)d_in[3];
    float* out = (float*)d_out;

    const size_t per = (size_t)BATCH_N * L_SEQ * DH;   // 4,194,304
    unsigned short* Qw  = (unsigned short*)d_ws;
    unsigned short* Kw  = Qw + per;
    unsigned short* Vtw = Kw + per;
    unsigned short* Xbw = Vtw + per;                   // 16,777,216 elems
    unsigned short* Wtw = Xbw + (size_t)16384 * HID;   // 786,432 elems
    float2* tabQ = (float2*)(Wtw + 786432);            // 4 MB (8B-aligned)
    float2* tabK = tabQ + (size_t)128 * L_SEQ;         // 4 MB
    // total workspace: ~68.3 MB

    // one fused prep dispatch: convert X, build tables, transpose W, zero O
    prep_kernel<<<19136, 256, 0, stream>>>(X, Xbw, tabQ, tabK,
                                           WQ, WK, WV, Wtw, out);

    gemm_qkv_kernel<<<768, 256, 0, stream>>>(Wtw, Xbw, tabQ, tabK, Qw, Kw, Vtw);

    retention_kernel<<<512, 256, 0, stream>>>(Qw, Kw, Vtw, out);
}